// Round 2
// baseline (3734.203 us; speedup 1.0000x reference)
//
#include <hip/hip_runtime.h>
#include <hip/hip_bf16.h>

// Problem dims: BS=4, N=512, Bb=8, Cc=8, D=128, H=512, DP=64, G=64
// All inputs/outputs are float32 (per reference setup_inputs / return dtypes).
// Output element offsets (f32 elements, flat concat in return order)
constexpr long XO = 0;               // x_out   (4,512,64,128) 16777216
constexpr long ZO = 16777216;        // z       (4,512,64,64)   8388608
constexpr long ZH = 25165824;        // z_hat   (4,512,64,64)   8388608
constexpr long SO = 33554432;        // surprise(4,512,64)       131072
constexpr long KC = 33685504;        // k_cand  (...,128)      16777216
constexpr long VP = 50462720;        // v_post                 16777216
constexpr long GA = 67239936;        // gate                     131072
constexpr long QN = 67371008;        // q_nov                  16777216
constexpr long VC = 84148224;        // v_cand                 16777216
constexpr long WN = 100925440;       // w_nov                    131072

__device__ __forceinline__ float wred64(float v){
#pragma unroll
  for (int off = 32; off; off >>= 1) v += __shfl_xor(v, off, 64);
  return v;
}
__device__ __forceinline__ float wred32(float v){
#pragma unroll
  for (int off = 16; off; off >>= 1) v += __shfl_xor(v, off, 64);
  return v;
}
__device__ __forceinline__ float gelu_exact(float x){
  return x * 0.5f * (1.f + erff(x * 0.70710678118654752f));
}

// ---------------- Kernel A: latent LN + 8x8 attention + wo residual ------------
// one block per (s,n,b); 8 tokens (c=0..7) x 128 dims, contiguous 1024 elements.
__global__ __launch_bounds__(256) void attn_kernel(
    const float* __restrict__ x_col,
    const float* __restrict__ lat_g, const float* __restrict__ lat_b,
    const float* __restrict__ wq, const float* __restrict__ bq,
    const float* __restrict__ wk, const float* __restrict__ bk,
    const float* __restrict__ wv, const float* __restrict__ bv,
    const float* __restrict__ wo, const float* __restrict__ bo,
    float* __restrict__ xattn)
{
  __shared__ float xs[8][128], hs[8][128], qs[8][128], ks[8][128], vs[8][128], os_[8][128];
  __shared__ float att[8][8];
  const int t = threadIdx.x;
  const long base = (long)blockIdx.x * 1024;

#pragma unroll
  for (int i = 0; i < 4; ++i) {
    int idx = t + i * 256;
    xs[idx >> 7][idx & 127] = x_col[base + idx];
  }
  __syncthreads();

  // LN over d=128, 32 threads per token
  {
    int c = t >> 5, j = t & 31;
    float s = 0.f, ss = 0.f;
#pragma unroll
    for (int m = 0; m < 4; ++m) { float v = xs[c][j + 32 * m]; s += v; ss += v * v; }
    s = wred32(s); ss = wred32(ss);
    float mean = s * (1.f / 128.f);
    float var  = ss * (1.f / 128.f) - mean * mean;
    float rsq  = rsqrtf(var + 1e-5f);
#pragma unroll
    for (int m = 0; m < 4; ++m) {
      int idx = j + 32 * m;
      hs[c][idx] = (xs[c][idx] - mean) * rsq * lat_g[idx] + lat_b[idx];
    }
  }
  __syncthreads();

  const int e  = t & 127;
  const int c0 = (t >> 7) * 4;   // tokens c0..c0+3

  // q,k,v projections (128x128 each), weight load amortized over 4 tokens
  {
    float aq[4] = {0,0,0,0}, ak[4] = {0,0,0,0}, av[4] = {0,0,0,0};
    for (int kk = 0; kk < 128; ++kk) {
      float wqv = wq[kk * 128 + e];
      float wkv = wk[kk * 128 + e];
      float wvv = wv[kk * 128 + e];
#pragma unroll
      for (int c4 = 0; c4 < 4; ++c4) {
        float hv = hs[c0 + c4][kk];
        aq[c4] += hv * wqv; ak[c4] += hv * wkv; av[c4] += hv * wvv;
      }
    }
    float bqv = bq[e], bkv = bk[e], bvv = bv[e];
#pragma unroll
    for (int c4 = 0; c4 < 4; ++c4) {
      qs[c0 + c4][e] = aq[c4] + bqv;
      ks[c0 + c4][e] = ak[c4] + bkv;
      vs[c0 + c4][e] = av[c4] + bvv;
    }
  }
  __syncthreads();

  // scores (8x8) * d^-0.5
  if (t < 64) {
    int c = t >> 3, e2 = t & 7;
    float acc = 0.f;
    for (int kk = 0; kk < 128; ++kk) acc += qs[c][kk] * ks[e2][kk];
    att[c][e2] = acc * 0.08838834764831845f;
  }
  __syncthreads();
  // softmax over e2
  if (t < 8) {
    float mx = -1e30f;
#pragma unroll
    for (int e2 = 0; e2 < 8; ++e2) mx = fmaxf(mx, att[t][e2]);
    float sum = 0.f, ex[8];
#pragma unroll
    for (int e2 = 0; e2 < 8; ++e2) { ex[e2] = expf(att[t][e2] - mx); sum += ex[e2]; }
    float inv = 1.f / sum;
#pragma unroll
    for (int e2 = 0; e2 < 8; ++e2) att[t][e2] = ex[e2] * inv;
  }
  __syncthreads();

  // o = att @ v
#pragma unroll
  for (int c4 = 0; c4 < 4; ++c4) {
    int c = c0 + c4;
    float acc = 0.f;
#pragma unroll
    for (int e2 = 0; e2 < 8; ++e2) acc += att[c][e2] * vs[e2][e];
    os_[c][e] = acc;
  }
  __syncthreads();

  // out = x + o @ wo + bo
  {
    float ao[4] = {0,0,0,0};
    for (int kk = 0; kk < 128; ++kk) {
      float wov = wo[kk * 128 + e];
#pragma unroll
      for (int c4 = 0; c4 < 4; ++c4) ao[c4] += os_[c0 + c4][kk] * wov;
    }
    float bov = bo[e];
#pragma unroll
    for (int c4 = 0; c4 < 4; ++c4) {
      int c = c0 + c4;
      xattn[base + c * 128 + e] = xs[c][e] + ao[c4] + bov;
    }
  }
}

// ---------------- Kernel B: everything after attention --------------------------
// one block per (g, chunk of 8 tokens with same g). tokens tok = (chunk*8+tk)*64+g
__global__ __launch_bounds__(256) void col_kernel(
    const float* __restrict__ zhp,
    const float* __restrict__ ln_g, const float* __restrict__ ln_b,
    const float* __restrict__ up_w, const float* __restrict__ up_b,
    const float* __restrict__ down_w, const float* __restrict__ down_b,
    const float* __restrict__ post_w, const float* __restrict__ post_b,
    const float* __restrict__ enc_w, const float* __restrict__ enc_b,
    const float* __restrict__ pred_w, const float* __restrict__ pred_b,
    const float* __restrict__ gain_w, const float* __restrict__ gain_b,
    float* __restrict__ out)
{
  __shared__ float xs[8][128];
  __shared__ float zh[8][64];
  __shared__ float zv[8][64];
  __shared__ float dl[8][64];
  __shared__ float gn[8][128];
  __shared__ float hn[8][128];
  __shared__ float big[8][512];     // hm (up output) then reused for post proj
  __shared__ float part[256][9];    // down partials, padded (9) for bank-conflict-free
  __shared__ float xo[8][128];

  const int t = threadIdx.x;
  const int g = blockIdx.x & 63;
  const int chunk = blockIdx.x >> 6;
  const long tok0 = (long)(chunk * 8) * 64 + g;    // token index for tk=0; stride 64 per tk

  // load x_attn (staged f32 in x_out slot) and z_hat_prev
#pragma unroll
  for (int i = 0; i < 4; ++i) {
    int idx = t + i * 256;               // 0..1023
    int tk = idx >> 7, o = idx & 127;
    xs[tk][o] = out[(tok0 + tk * 64) * 128 + o];
  }
#pragma unroll
  for (int i = 0; i < 2; ++i) {
    int idx = t + i * 256;               // 0..511
    int tk = idx >> 6, o = idx & 63;
    zh[tk][o] = zhp[(tok0 + tk * 64) * 64 + o];
  }
  __syncthreads();

  // enc: z = x @ enc_w[g] + enc_b ; delta, surprise, gate.  one wave per token, 2 passes
  {
    const int o = t & 63, tq = t >> 6;   // tq = wave id 0..3
    const float* w = enc_w + (long)g * (128 * 64) + o;
    float bias = enc_b[g * 64 + o];
#pragma unroll
    for (int pass = 0; pass < 2; ++pass) {
      int tk = tq + pass * 4;
      float acc = bias;
      for (int kk = 0; kk < 128; ++kk) acc += xs[tk][kk] * w[kk * 64];
      zv[tk][o] = acc;
      float d = acc - zh[tk][o];
      dl[tk][o] = d;
      out[ZO + (tok0 + tk * 64) * 64 + o] = acc;
      float s2 = wred64(d * d);
      if (o == 0) {
        float sur = sqrtf(s2);
        out[SO + tok0 + tk * 64] = sur;
        out[GA + tok0 + tk * 64] = fminf(sur, 1.f);  // clip(sur/1.0, 0, 1), sur>=0
      }
    }
  }
  __syncthreads();

  // pred: z_hat = z @ pred_w[g] + pred_b
  {
    const int o = t & 63, tq = t >> 6;
    const float* w = pred_w + (long)g * (64 * 64) + o;
    float bias = pred_b[g * 64 + o];
#pragma unroll
    for (int pass = 0; pass < 2; ++pass) {
      int tk = tq + pass * 4;
      float acc = bias;
      for (int kk = 0; kk < 64; ++kk) acc += zv[tk][kk] * w[kk * 64];
      out[ZH + (tok0 + tk * 64) * 64 + o] = acc;
    }
  }

  // gain = 1 + 0.1*tanh(delta @ gain_w[g] + gain_b)   (4 tokens per thread)
  {
    const int o = t & 127, tb = t >> 7;  // tokens tb, tb+2, tb+4, tb+6
    const float* w = gain_w + (long)g * (64 * 128) + o;
    float bias = gain_b[g * 128 + o];
    float acc[4] = {bias, bias, bias, bias};
    for (int kk = 0; kk < 64; ++kk) {
      float wv = w[kk * 128];
#pragma unroll
      for (int m = 0; m < 4; ++m) acc[m] += dl[tb + m * 2][kk] * wv;
    }
#pragma unroll
    for (int m = 0; m < 4; ++m) gn[tb + m * 2][o] = 1.f + 0.1f * tanhf(acc[m]);
  }

  // group LN (per token, 32 threads each) -> hn (without gain yet)
  {
    int tk = t >> 5, j = t & 31;
    float s = 0.f, ss = 0.f;
#pragma unroll
    for (int m = 0; m < 4; ++m) { float v = xs[tk][j + 32 * m]; s += v; ss += v * v; }
    s = wred32(s); ss = wred32(ss);
    float mean = s * (1.f / 128.f);
    float var  = ss * (1.f / 128.f) - mean * mean;
    float rsq  = rsqrtf(var + 1e-5f);
#pragma unroll
    for (int m = 0; m < 4; ++m) {
      int o = j + 32 * m;
      hn[tk][o] = (xs[tk][o] - mean) * rsq * ln_g[g * 128 + o] + ln_b[g * 128 + o];
    }
  }
  __syncthreads();

  // apply gain
#pragma unroll
  for (int i = 0; i < 4; ++i) {
    int idx = t + i * 256;
    int tk = idx >> 7, o = idx & 127;
    hn[tk][o] *= gn[tk][o];
  }
  __syncthreads();

  // up (128->512) + exact GELU; each thread: outputs t and t+256 for all 8 tokens
  {
    const float* w = up_w + (long)g * (128 * 512);
    float b0 = up_b[g * 512 + t];
    float b1 = up_b[g * 512 + t + 256];
    float a0[8], a1[8];
#pragma unroll
    for (int tk = 0; tk < 8; ++tk) { a0[tk] = b0; a1[tk] = b1; }
    for (int kk = 0; kk < 128; ++kk) {
      float w0 = w[kk * 512 + t];
      float w1 = w[kk * 512 + t + 256];
#pragma unroll
      for (int tk = 0; tk < 8; ++tk) {
        float hv = hn[tk][kk];
        a0[tk] += hv * w0; a1[tk] += hv * w1;
      }
    }
#pragma unroll
    for (int tk = 0; tk < 8; ++tk) {
      big[tk][t]       = gelu_exact(a0[tk]);
      big[tk][t + 256] = gelu_exact(a1[tk]);
    }
  }
  __syncthreads();

  // down (512->128): split K over 2 halves of the block
  {
    const int o = t & 127, hf = t >> 7;
    const float* w = down_w + (long)g * (512 * 128) + o;
    float acc[8] = {0,0,0,0,0,0,0,0};
    for (int kk = hf * 256; kk < hf * 256 + 256; ++kk) {
      float wv = w[(long)kk * 128];
#pragma unroll
      for (int tk = 0; tk < 8; ++tk) acc[tk] += big[tk][kk] * wv;
    }
#pragma unroll
    for (int tk = 0; tk < 8; ++tk) part[t][tk] = acc[tk];
  }
  __syncthreads();
  if (t < 128) {
    float bias = down_b[g * 128 + t];
#pragma unroll
    for (int tk = 0; tk < 8; ++tk) {
      float hh = part[t][tk] + part[t + 128][tk] + bias;
      float v = xs[tk][t] + hh;
      xo[tk][t] = v;
      out[(tok0 + tk * 64) * 128 + t] = v;   // final x_out
    }
  }
  __syncthreads();

  // post projection (128 -> 513); outputs t and t+256 per token into big[][0..511]
  {
    const float* w = post_w + (long)g * (128 * 513);
    float b0 = post_b[g * 513 + t];
    float b1 = post_b[g * 513 + t + 256];
    float a0[8], a1[8];
#pragma unroll
    for (int tk = 0; tk < 8; ++tk) { a0[tk] = b0; a1[tk] = b1; }
    for (int kk = 0; kk < 128; ++kk) {
      float w0 = w[kk * 513 + t];
      float w1 = w[kk * 513 + t + 256];
#pragma unroll
      for (int tk = 0; tk < 8; ++tk) {
        float xv = xo[tk][kk];
        a0[tk] += xv * w0; a1[tk] += xv * w1;
      }
    }
#pragma unroll
    for (int tk = 0; tk < 8; ++tk) { big[tk][t] = a0[tk]; big[tk][t + 256] = a1[tk]; }
  }
  // column 512 (novelty logit) + w_nov: wave0, 8 lanes per token
  if (t < 64) {
    int tk = t >> 3, j = t & 7;
    const float* w = post_w + (long)g * (128 * 513) + 512;
    float p = 0.f;
    for (int kk = j * 16; kk < j * 16 + 16; ++kk) p += xo[tk][kk] * w[(long)kk * 513];
    p += __shfl_xor(p, 1, 64);
    p += __shfl_xor(p, 2, 64);
    p += __shfl_xor(p, 4, 64);
    if (j == 0) {
      float nv = p + post_b[g * 513 + 512];
      out[WN + tok0 + tk * 64] = 1.f / (1.f + expf(-nv));
    }
  }
  __syncthreads();

  // norms of k_pre (big[0:128]) and k_cand_raw (big[256:384]); write 4 slice outputs
  {
    int tk = t >> 5, j = t & 31;
    float s1 = 0.f, s2 = 0.f;
#pragma unroll
    for (int m = 0; m < 4; ++m) {
      float v1 = big[tk][j + 32 * m];
      float v2 = big[tk][256 + j + 32 * m];
      s1 += v1 * v1; s2 += v2 * v2;
    }
    s1 = wred32(s1); s2 = wred32(s2);
    float i1 = 1.f / fmaxf(sqrtf(s1), 1e-6f);
    float i2 = 1.f / fmaxf(sqrtf(s2), 1e-6f);
    long ob = (tok0 + tk * 64) * 128;
#pragma unroll
    for (int m = 0; m < 4; ++m) {
      int o = j + 32 * m;
      out[KC + ob + o] = big[tk][o] * i1;
      out[VP + ob + o] = big[tk][128 + o];
      out[QN + ob + o] = big[tk][256 + o] * i2;
      out[VC + ob + o] = big[tk][384 + o];
    }
  }
}

extern "C" void kernel_launch(void* const* d_in, const int* in_sizes, int n_in,
                              void* d_out, int out_size, void* d_ws, size_t ws_size,
                              hipStream_t stream) {
  (void)in_sizes; (void)n_in; (void)out_size; (void)d_ws; (void)ws_size;
  const float* x_col  = (const float*)d_in[0];
  const float* zhp    = (const float*)d_in[1];
  const float* ln_g   = (const float*)d_in[2];
  const float* ln_b   = (const float*)d_in[3];
  const float* up_w   = (const float*)d_in[4];
  const float* up_b   = (const float*)d_in[5];
  const float* down_w = (const float*)d_in[6];
  const float* down_b = (const float*)d_in[7];
  const float* lat_g  = (const float*)d_in[8];
  const float* lat_b  = (const float*)d_in[9];
  const float* wq     = (const float*)d_in[10];
  const float* bq     = (const float*)d_in[11];
  const float* wk     = (const float*)d_in[12];
  const float* bk     = (const float*)d_in[13];
  const float* wv     = (const float*)d_in[14];
  const float* bv     = (const float*)d_in[15];
  const float* wo     = (const float*)d_in[16];
  const float* bo     = (const float*)d_in[17];
  const float* post_w = (const float*)d_in[18];
  const float* post_b = (const float*)d_in[19];
  const float* enc_w  = (const float*)d_in[20];
  const float* enc_b  = (const float*)d_in[21];
  const float* pred_w = (const float*)d_in[22];
  const float* pred_b = (const float*)d_in[23];
  const float* gain_w = (const float*)d_in[24];
  const float* gain_b = (const float*)d_in[25];
  float* out = (float*)d_out;

  // Kernel A: 4*512*8 = 16384 blocks (s,n,b); stages x_attn f32 into x_out slot
  attn_kernel<<<dim3(16384), dim3(256), 0, stream>>>(
      x_col, lat_g, lat_b, wq, bq, wk, bk, wv, bv, wo, bo, out);
  // Kernel B: 64 groups * 256 chunks of 8 tokens = 16384 blocks
  col_kernel<<<dim3(16384), dim3(256), 0, stream>>>(
      zhp, ln_g, ln_b, up_w, up_b, down_w, down_b, post_w, post_b,
      enc_w, enc_b, pred_w, pred_b, gain_w, gain_b, out);
}